// Round 1
// baseline (899.192 us; speedup 1.0000x reference)
//
#include <hip/hip_runtime.h>

typedef __bf16 bfv8 __attribute__((ext_vector_type(8)));
typedef short s16x8 __attribute__((ext_vector_type(8)));
typedef short s16x4 __attribute__((ext_vector_type(4)));
typedef float f32x4 __attribute__((ext_vector_type(4)));

#define MFMA(a, b, c) __builtin_amdgcn_mfma_f32_16x16x32_bf16(a, b, c, 0, 0, 0)

__device__ __forceinline__ short f2bf(float f) {
  union { float f; unsigned u; } v; v.f = f;
  unsigned r = v.u + 0x7FFFu + ((v.u >> 16) & 1u);
  return (short)(r >> 16);
}
__device__ __forceinline__ float bf2f(short s) {
  union { unsigned u; float f; } v; v.u = ((unsigned)(unsigned short)s) << 16;
  return v.f;
}

// ---------------------------------------------------------------- weights cvt
__global__ __launch_bounds__(256) void convert_w(const float* __restrict__ qkvw,
                                                 const float* __restrict__ projw,
                                                 short* __restrict__ wq,
                                                 short* __restrict__ wp) {
  const int n1 = 2304 * 768 / 4;  // 442368
  const int n2 = 768 * 768 / 4;   // 147456
  int idx = blockIdx.x * 256 + threadIdx.x;
  if (idx < n1) {
    float4 v = ((const float4*)qkvw)[idx];
    s16x4 s = {f2bf(v.x), f2bf(v.y), f2bf(v.z), f2bf(v.w)};
    *(s16x4*)(wq + idx * 4) = s;
  } else if (idx < n1 + n2) {
    int i = idx - n1;
    float4 v = ((const float4*)projw)[i];
    s16x4 s = {f2bf(v.x), f2bf(v.y), f2bf(v.z), f2bf(v.w)};
    *(s16x4*)(wp + i * 4) = s;
  }
}

// ---------------------------------------------------------------- qkv gemm
// rows = tokens in window-partitioned order (50176), cols = 2304 (qkv)
__global__ __launch_bounds__(256) void qkv_gemm(const float* __restrict__ x,
                                                const short* __restrict__ wq,
                                                const float* __restrict__ qkvb,
                                                short* __restrict__ Q,
                                                short* __restrict__ K,
                                                short* __restrict__ V) {
  __shared__ short As[128 * 40];
  __shared__ short Bs[128 * 40];
  const int bid = blockIdx.x;
  const int bn = bid % 18, bm = bid / 18;
  const int tid = threadIdx.x, lane = tid & 63, wave = tid >> 6;
  const int row0 = (wave >> 1) * 64, col0 = (wave & 1) * 64;
  const int li = lane & 15, g8 = (lane >> 4) * 8;

  // Precompute gathered A-row base offsets (window partition of x)
  int abase[4], arow[4];
#pragma unroll
  for (int it = 0; it < 4; ++it) {
    int rr = (tid >> 3) + it * 32;
    int t = bm * 128 + rr;
    int wdx = t / 196, n = t - wdx * 196;
    int b = wdx >> 4, wl = wdx & 15;
    int hh = (wl >> 2) * 14 + n / 14;
    int ww = (wl & 3) * 14 + (n - (n / 14) * 14);
    abase[it] = ((b * 56 + hh) * 56 + ww) * 768 + ((tid & 7) << 2);
    arow[it] = rr;
  }
  const int bjj0 = tid >> 2;
  const int bseg = (tid & 3) * 8;

  f32x4 acc[4][4];
#pragma unroll
  for (int i = 0; i < 4; ++i)
#pragma unroll
    for (int j = 0; j < 4; ++j) acc[i][j] = (f32x4){0.f, 0.f, 0.f, 0.f};

  for (int k0 = 0; k0 < 768; k0 += 32) {
#pragma unroll
    for (int it = 0; it < 4; ++it) {
      float4 v = *(const float4*)(x + abase[it] + k0);
      s16x4 s = {f2bf(v.x), f2bf(v.y), f2bf(v.z), f2bf(v.w)};
      *(s16x4*)&As[arow[it] * 40 + ((tid & 7) << 2)] = s;
    }
#pragma unroll
    for (int it = 0; it < 2; ++it) {
      int jj = bjj0 + it * 64;
      s16x8 w = *(const s16x8*)(wq + (bn * 128 + jj) * 768 + k0 + bseg);
      *(s16x8*)&Bs[jj * 40 + bseg] = w;
    }
    __syncthreads();
    bfv8 af[4], bfr[4];
#pragma unroll
    for (int mi = 0; mi < 4; ++mi)
      af[mi] = *(const bfv8*)&As[(row0 + mi * 16 + li) * 40 + g8];
#pragma unroll
    for (int ni = 0; ni < 4; ++ni)
      bfr[ni] = *(const bfv8*)&Bs[(col0 + ni * 16 + li) * 40 + g8];
#pragma unroll
    for (int mi = 0; mi < 4; ++mi)
#pragma unroll
      for (int ni = 0; ni < 4; ++ni)
        acc[mi][ni] = MFMA(af[mi], bfr[ni], acc[mi][ni]);
    __syncthreads();
  }

  const int g4 = (lane >> 4) * 4;
#pragma unroll
  for (int mi = 0; mi < 4; ++mi) {
    int rbase = bm * 128 + row0 + mi * 16 + g4;
#pragma unroll
    for (int ni = 0; ni < 4; ++ni) {
      int col = bn * 128 + col0 + ni * 16 + li;
      int which = col / 768;
      int cm = col - which * 768;
      int head = cm >> 6, d = cm & 63;
      short* dst = (which == 0) ? Q : ((which == 1) ? K : V);
      float bias = qkvb[col];
      f32x4 a = acc[mi][ni];
#pragma unroll
      for (int j = 0; j < 4; ++j) {
        int t = rbase + j;
        int wdx = t / 196, n = t - wdx * 196;
        dst[((wdx * 12 + head) * 196 + n) * 64 + d] = f2bf(a[j] + bias);
      }
    }
  }
}

// ---------------------------------------------------------------- attention
// one block per (window, head); 256 threads = 4 waves; m-tiles of 16 rows
__global__ __launch_bounds__(256) void attn_kernel(const short* __restrict__ Q,
                                                   const short* __restrict__ K,
                                                   const short* __restrict__ V,
                                                   const float* __restrict__ rph,
                                                   const float* __restrict__ rpw,
                                                   short* __restrict__ AO) {
  __shared__ short Ks[196 * 72];     // keys, K-contig rows (pad 72)
  __shared__ short Vt[64 * 232];     // V transposed [d][k], k padded to 224(+8)
  __shared__ short Rh[32 * 72];      // rel_pos_h bf16 (27 rows + zero pad)
  __shared__ short Rw[32 * 72];
  __shared__ short relh[208 * 32];   // relall_h[r][p] bf16
  __shared__ short relw[208 * 32];
  __shared__ short Ps[4 * 16 * 232]; // per-wave P tile

  const int bh = blockIdx.x;
  const int wdx = bh / 12, head = bh - wdx * 12;
  const int tid = threadIdx.x, lane = tid & 63, wave = tid >> 6;
  const int li = lane & 15, g = lane >> 4, g8 = g * 8;
  const short* Qb = Q + bh * 12544;
  const short* Kb = K + bh * 12544;
  const short* Vb = V + bh * 12544;

  // phase 0: zero pad regions (Vt, Ps, Rh, Rw fully)
  {
    int* z = (int*)Vt;
    for (int i = tid; i < 64 * 232 / 2; i += 256) z[i] = 0;
    int* z2 = (int*)Ps;
    for (int i = tid; i < 4 * 16 * 232 / 2; i += 256) z2[i] = 0;
    int* z3 = (int*)Rh;
    for (int i = tid; i < 32 * 72 / 2; i += 256) z3[i] = 0;
    int* z4 = (int*)Rw;
    for (int i = tid; i < 32 * 72 / 2; i += 256) z4[i] = 0;
  }
  __syncthreads();

  // phase 1: stage K, V^T, rel tables
  for (int t = tid; t < 1568; t += 256) {  // 196 rows x 8 segs
    int rr = t >> 3, seg = (t & 7) * 8;
    s16x8 kv = *(const s16x8*)(Kb + rr * 64 + seg);
    *(s16x8*)&Ks[rr * 72 + seg] = kv;
  }
  for (int t = tid; t < 784; t += 256) {  // 98 key-pairs x 8 d-segs
    int dseg = t / 98;
    int kp = t - dseg * 98;
    int d0 = dseg * 8;
    s16x8 a = *(const s16x8*)(Vb + (2 * kp) * 64 + d0);
    s16x8 b = *(const s16x8*)(Vb + (2 * kp + 1) * 64 + d0);
#pragma unroll
    for (int i = 0; i < 8; ++i) {
      *(short2*)&Vt[(d0 + i) * 232 + 2 * kp] = make_short2(a[i], b[i]);
    }
  }
  for (int t = tid; t < 216; t += 256) {  // 27 rows x 8 segs of rel tables
    int p = t >> 3, seg = (t & 7) * 8;
    float4 a0 = *(const float4*)(rph + p * 64 + seg);
    float4 a1 = *(const float4*)(rph + p * 64 + seg + 4);
    s16x4 s0 = {f2bf(a0.x), f2bf(a0.y), f2bf(a0.z), f2bf(a0.w)};
    s16x4 s1 = {f2bf(a1.x), f2bf(a1.y), f2bf(a1.z), f2bf(a1.w)};
    *(s16x4*)&Rh[p * 72 + seg] = s0;
    *(s16x4*)&Rh[p * 72 + seg + 4] = s1;
    float4 b0 = *(const float4*)(rpw + p * 64 + seg);
    float4 b1 = *(const float4*)(rpw + p * 64 + seg + 4);
    s16x4 t0 = {f2bf(b0.x), f2bf(b0.y), f2bf(b0.z), f2bf(b0.w)};
    s16x4 t1 = {f2bf(b1.x), f2bf(b1.y), f2bf(b1.z), f2bf(b1.w)};
    *(s16x4*)&Rw[p * 72 + seg] = t0;
    *(s16x4*)&Rw[p * 72 + seg + 4] = t1;
  }
  __syncthreads();

  short* myP = &Ps[wave * (16 * 232)];

  for (int mt = wave; mt < 13; mt += 4) {
    const int m0 = mt * 16;
    int qrow = m0 + li;
    if (qrow > 195) qrow = 195;
    const bfv8 qa0 = *(const bfv8*)(Qb + qrow * 64 + g8);
    const bfv8 qa1 = *(const bfv8*)(Qb + qrow * 64 + 32 + g8);

    // rel-pos mini-GEMMs: relall[m][p] = q[m] . rel_pos[p]
#pragma unroll
    for (int n = 0; n < 2; ++n) {
      const bfv8 rh0 = *(const bfv8*)&Rh[(n * 16 + li) * 72 + g8];
      const bfv8 rh1 = *(const bfv8*)&Rh[(n * 16 + li) * 72 + 32 + g8];
      f32x4 th = (f32x4){0.f, 0.f, 0.f, 0.f};
      th = MFMA(qa0, rh0, th);
      th = MFMA(qa1, rh1, th);
      const bfv8 rw0 = *(const bfv8*)&Rw[(n * 16 + li) * 72 + g8];
      const bfv8 rw1 = *(const bfv8*)&Rw[(n * 16 + li) * 72 + 32 + g8];
      f32x4 tw = (f32x4){0.f, 0.f, 0.f, 0.f};
      tw = MFMA(qa0, rw0, tw);
      tw = MFMA(qa1, rw1, tw);
#pragma unroll
      for (int j = 0; j < 4; ++j) {
        int r = m0 + g * 4 + j;
        relh[r * 32 + n * 16 + li] = f2bf(th[j]);
        relw[r * 32 + n * 16 + li] = f2bf(tw[j]);
      }
    }

    // S = Q K^T
    f32x4 sa[13];
#pragma unroll
    for (int nt = 0; nt < 13; ++nt) {
      sa[nt] = (f32x4){0.f, 0.f, 0.f, 0.f};
      int krow = nt * 16 + li;
      if (krow > 195) krow = 195;
      const bfv8 kb0 = *(const bfv8*)&Ks[krow * 72 + g8];
      const bfv8 kb1 = *(const bfv8*)&Ks[krow * 72 + 32 + g8];
      sa[nt] = MFMA(qa0, kb0, sa[nt]);
      sa[nt] = MFMA(qa1, kb1, sa[nt]);
    }

    // bias + scale + row max
    int rj[4], hrj[4], wrj[4];
#pragma unroll
    for (int j = 0; j < 4; ++j) {
      rj[j] = m0 + g * 4 + j;
      hrj[j] = rj[j] / 14;
      wrj[j] = rj[j] - hrj[j] * 14;
    }
    float mx[4] = {-3e38f, -3e38f, -3e38f, -3e38f};
#pragma unroll
    for (int nt = 0; nt < 13; ++nt) {
      int c = nt * 16 + li;
      bool valid = c < 196;
      int kh = c / 14;
      int kw = c - kh * 14;
#pragma unroll
      for (int j = 0; j < 4; ++j) {
        float s;
        if (valid) {
          s = sa[nt][j] * 0.125f + bf2f(relh[rj[j] * 32 + hrj[j] - kh + 13]) +
              bf2f(relw[rj[j] * 32 + wrj[j] - kw + 13]);
        } else {
          s = -3e38f;
        }
        sa[nt][j] = s;
        mx[j] = fmaxf(mx[j], s);
      }
    }
#pragma unroll
    for (int j = 0; j < 4; ++j) {
      mx[j] = fmaxf(mx[j], __shfl_xor(mx[j], 1));
      mx[j] = fmaxf(mx[j], __shfl_xor(mx[j], 2));
      mx[j] = fmaxf(mx[j], __shfl_xor(mx[j], 4));
      mx[j] = fmaxf(mx[j], __shfl_xor(mx[j], 8));
    }
    float sum[4] = {0.f, 0.f, 0.f, 0.f};
#pragma unroll
    for (int nt = 0; nt < 13; ++nt) {
#pragma unroll
      for (int j = 0; j < 4; ++j) {
        float p = __expf(sa[nt][j] - mx[j]);
        sa[nt][j] = p;
        sum[j] += p;
      }
    }
#pragma unroll
    for (int j = 0; j < 4; ++j) {
      sum[j] += __shfl_xor(sum[j], 1);
      sum[j] += __shfl_xor(sum[j], 2);
      sum[j] += __shfl_xor(sum[j], 4);
      sum[j] += __shfl_xor(sum[j], 8);
    }
    float inv[4];
#pragma unroll
    for (int j = 0; j < 4; ++j) inv[j] = 1.0f / sum[j];

    // write normalized P to LDS
#pragma unroll
    for (int nt = 0; nt < 13; ++nt) {
      int c = nt * 16 + li;
#pragma unroll
      for (int j = 0; j < 4; ++j)
        myP[(g * 4 + j) * 232 + c] = f2bf(sa[nt][j] * inv[j]);
    }

    // O = P V
    f32x4 oa[4];
#pragma unroll
    for (int dn = 0; dn < 4; ++dn) oa[dn] = (f32x4){0.f, 0.f, 0.f, 0.f};
#pragma unroll
    for (int kt = 0; kt < 7; ++kt) {
      const bfv8 pa = *(const bfv8*)&myP[li * 232 + kt * 32 + g8];
#pragma unroll
      for (int dn = 0; dn < 4; ++dn) {
        const bfv8 vb = *(const bfv8*)&Vt[(dn * 16 + li) * 232 + kt * 32 + g8];
        oa[dn] = MFMA(pa, vb, oa[dn]);
      }
    }
#pragma unroll
    for (int dn = 0; dn < 4; ++dn)
#pragma unroll
      for (int j = 0; j < 4; ++j) {
        int r = m0 + g * 4 + j;
        if (r < 196)
          AO[(wdx * 196 + r) * 768 + head * 64 + dn * 16 + li] = f2bf(oa[dn][j]);
      }
  }
}

// ---------------------------------------------------------------- proj gemm
__global__ __launch_bounds__(256) void proj_gemm(const short* __restrict__ AO,
                                                 const short* __restrict__ wp,
                                                 const float* __restrict__ projb,
                                                 float* __restrict__ out) {
  __shared__ short As[128 * 40];
  __shared__ short Bs[128 * 40];
  const int bid = blockIdx.x;
  const int bn = bid % 6, bm = bid / 6;
  const int tid = threadIdx.x, lane = tid & 63, wave = tid >> 6;
  const int row0 = (wave >> 1) * 64, col0 = (wave & 1) * 64;
  const int li = lane & 15, g8 = (lane >> 4) * 8;
  const int bjj0 = tid >> 2;
  const int bseg = (tid & 3) * 8;

  f32x4 acc[4][4];
#pragma unroll
  for (int i = 0; i < 4; ++i)
#pragma unroll
    for (int j = 0; j < 4; ++j) acc[i][j] = (f32x4){0.f, 0.f, 0.f, 0.f};

  for (int k0 = 0; k0 < 768; k0 += 32) {
#pragma unroll
    for (int it = 0; it < 2; ++it) {
      int task = tid + it * 256;
      int rr = task >> 2;
      int seg = (task & 3) * 8;
      s16x8 v = *(const s16x8*)(AO + (bm * 128 + rr) * 768 + k0 + seg);
      *(s16x8*)&As[rr * 40 + seg] = v;
    }
#pragma unroll
    for (int it = 0; it < 2; ++it) {
      int jj = bjj0 + it * 64;
      s16x8 w = *(const s16x8*)(wp + (bn * 128 + jj) * 768 + k0 + bseg);
      *(s16x8*)&Bs[jj * 40 + bseg] = w;
    }
    __syncthreads();
    bfv8 af[4], bfr[4];
#pragma unroll
    for (int mi = 0; mi < 4; ++mi)
      af[mi] = *(const bfv8*)&As[(row0 + mi * 16 + li) * 40 + g8];
#pragma unroll
    for (int ni = 0; ni < 4; ++ni)
      bfr[ni] = *(const bfv8*)&Bs[(col0 + ni * 16 + li) * 40 + g8];
#pragma unroll
    for (int mi = 0; mi < 4; ++mi)
#pragma unroll
      for (int ni = 0; ni < 4; ++ni)
        acc[mi][ni] = MFMA(af[mi], bfr[ni], acc[mi][ni]);
    __syncthreads();
  }

  const int g4 = (lane >> 4) * 4;
#pragma unroll
  for (int mi = 0; mi < 4; ++mi) {
    int rbase = bm * 128 + row0 + mi * 16 + g4;
#pragma unroll
    for (int ni = 0; ni < 4; ++ni) {
      int col = bn * 128 + col0 + ni * 16 + li;
      float bias = projb[col];
      f32x4 a = acc[mi][ni];
#pragma unroll
      for (int j = 0; j < 4; ++j) {
        int t = rbase + j;
        int wdx = t / 196, n = t - wdx * 196;
        int b = wdx >> 4, wl = wdx & 15;
        int hh = (wl >> 2) * 14 + n / 14;
        int ww = (wl & 3) * 14 + (n - (n / 14) * 14);
        out[((b * 56 + hh) * 56 + ww) * 768 + col] = a[j] + bias;
      }
    }
  }
}

// ---------------------------------------------------------------- launch
extern "C" void kernel_launch(void* const* d_in, const int* in_sizes, int n_in,
                              void* d_out, int out_size, void* d_ws, size_t ws_size,
                              hipStream_t stream) {
  const float* x = (const float*)d_in[0];
  const float* qkv_w = (const float*)d_in[1];
  const float* qkv_b = (const float*)d_in[2];
  const float* proj_w = (const float*)d_in[3];
  const float* proj_b = (const float*)d_in[4];
  const float* rph = (const float*)d_in[5];
  const float* rpw = (const float*)d_in[6];
  float* out = (float*)d_out;

  char* ws = (char*)d_ws;
  short* Q  = (short*)(ws);
  short* K  = (short*)(ws + 77070336);
  short* V  = (short*)(ws + 154140672);
  short* AO = (short*)(ws + 231211008);
  short* Wq = (short*)(ws + 308281344);
  short* Wp = (short*)(ws + 311820288);

  hipLaunchKernelGGL(convert_w, dim3(2304), dim3(256), 0, stream, qkv_w, proj_w, Wq, Wp);
  hipLaunchKernelGGL(qkv_gemm, dim3(7056), dim3(256), 0, stream, x, Wq, qkv_b, Q, K, V);
  hipLaunchKernelGGL(attn_kernel, dim3(3072), dim3(256), 0, stream, Q, K, V, rph, rpw, AO);
  hipLaunchKernelGGL(proj_gemm, dim3(2352), dim3(256), 0, stream, AO, Wp, proj_b, out);
}

// Round 2
// 754.563 us; speedup vs baseline: 1.1917x; 1.1917x over previous
//
#include <hip/hip_runtime.h>
#include <stdint.h>

typedef __bf16 bfv8 __attribute__((ext_vector_type(8)));
typedef short s16x8 __attribute__((ext_vector_type(8)));
typedef short s16x4 __attribute__((ext_vector_type(4)));
typedef float f32x4 __attribute__((ext_vector_type(4)));

#define MFMA(a, b, c) __builtin_amdgcn_mfma_f32_16x16x32_bf16(a, b, c, 0, 0, 0)

__device__ __forceinline__ short f2bf(float f) {
  union { float f; unsigned u; } v; v.f = f;
  unsigned r = v.u + 0x7FFFu + ((v.u >> 16) & 1u);
  return (short)(r >> 16);
}
__device__ __forceinline__ float bf2f(short s) {
  union { unsigned u; float f; } v; v.u = ((unsigned)(unsigned short)s) << 16;
  return v.f;
}

// async global->LDS, 16B per lane; lds base must be wave-uniform
__device__ __forceinline__ void async_cp16(const short* g, short* l) {
  auto gp = reinterpret_cast<const uint32_t __attribute__((address_space(1)))*>(
      reinterpret_cast<uintptr_t>(g));
  auto lp = reinterpret_cast<uint32_t __attribute__((address_space(3)))*>(
      reinterpret_cast<uintptr_t>(l));
  __builtin_amdgcn_global_load_lds(gp, lp, 16, 0, 0);
}

// ------------------------------------------------------------- convert pass
// x(f32,NHWC) -> Xbf (bf16, window-partitioned rows [50176][768])
// qkv_w/proj_w f32 -> bf16 ; rel tables -> bf16 padded [32][64]
__global__ __launch_bounds__(256) void convert_all(
    const float* __restrict__ x, const float* __restrict__ qkvw,
    const float* __restrict__ projw, const float* __restrict__ rph,
    const float* __restrict__ rpw, short* __restrict__ Xbf,
    short* __restrict__ Wq, short* __restrict__ Wp, short* __restrict__ Rhb,
    short* __restrict__ Rwb) {
  const int NX = 9633792;   // 50176*192
  const int NW1 = 442368;   // 2304*768/4
  const int NW2 = 147456;   // 768*768/4
  const int NR = 512;       // 32*16
  int idx = blockIdx.x * 256 + threadIdx.x;
  if (idx < NX) {
    int t = idx / 192, cq = idx - t * 192;
    int wdx = t / 196, n = t - wdx * 196;
    int b = wdx >> 4, wl = wdx & 15;
    int nh = n / 14;
    int hh = (wl >> 2) * 14 + nh;
    int ww = (wl & 3) * 14 + (n - nh * 14);
    float4 v = *(const float4*)(x + ((b * 56 + hh) * 56 + ww) * 768 + cq * 4);
    s16x4 s = {f2bf(v.x), f2bf(v.y), f2bf(v.z), f2bf(v.w)};
    *(s16x4*)(Xbf + idx * 4) = s;
  } else if (idx < NX + NW1) {
    int i = idx - NX;
    float4 v = ((const float4*)qkvw)[i];
    s16x4 s = {f2bf(v.x), f2bf(v.y), f2bf(v.z), f2bf(v.w)};
    *(s16x4*)(Wq + i * 4) = s;
  } else if (idx < NX + NW1 + NW2) {
    int i = idx - NX - NW1;
    float4 v = ((const float4*)projw)[i];
    s16x4 s = {f2bf(v.x), f2bf(v.y), f2bf(v.z), f2bf(v.w)};
    *(s16x4*)(Wp + i * 4) = s;
  } else if (idx < NX + NW1 + NW2 + 2 * NR) {
    int i = idx - NX - NW1 - NW2;
    int which = i >> 9;
    int j = i & 511;
    int p = j >> 4, q = j & 15;
    const float* src = which ? rpw : rph;
    short* dst = which ? Rwb : Rhb;
    s16x4 s = {0, 0, 0, 0};
    if (p < 27) {
      float4 v = *(const float4*)(src + p * 64 + q * 4);
      s = (s16x4){f2bf(v.x), f2bf(v.y), f2bf(v.z), f2bf(v.w)};
    }
    *(s16x4*)(dst + p * 64 + q * 4) = s;
  }
}

// ------------------------------------------------------------- qkv gemm
// C[50176][2304] = Xbf * Wq^T ; epilogue scatters into Q/K/V [wh][196][64]
__global__ __launch_bounds__(256) void qkv_gemm(
    const short* __restrict__ Xbf, const short* __restrict__ Wq,
    const float* __restrict__ qkvb, short* __restrict__ Q,
    short* __restrict__ K, short* __restrict__ V) {
  __shared__ short As[128 * 32];
  __shared__ short Bs[128 * 32];
  int bid = blockIdx.x;
  int wg = (bid & 7) * 882 + (bid >> 3);  // 7056 = 8*882, bijective
  int bm = wg / 18, bn = wg - bm * 18;
  const int tid = threadIdx.x, lane = tid & 63, wave = tid >> 6;
  const int row0 = (wave >> 1) * 64, col0 = (wave & 1) * 64;
  const int li = lane & 15, g8 = (lane >> 4) * 8;

  const int c0 = wave * 2;
  const int rr = c0 * 16 + (lane >> 2);
  const int seg = (lane & 3) * 8;
  const short* asrc = Xbf + (bm * 128 + rr) * 768 + seg;
  const short* bsrc = Wq + (bn * 128 + rr) * 768 + seg;
  short* alds0 = As + c0 * 512;
  short* alds1 = As + c0 * 512 + 512;
  short* blds0 = Bs + c0 * 512;
  short* blds1 = Bs + c0 * 512 + 512;

  f32x4 acc[4][4];
#pragma unroll
  for (int i = 0; i < 4; ++i)
#pragma unroll
    for (int j = 0; j < 4; ++j) acc[i][j] = (f32x4){0.f, 0.f, 0.f, 0.f};

  for (int k0 = 0; k0 < 768; k0 += 32) {
    async_cp16(asrc + k0, alds0);
    async_cp16(asrc + 16 * 768 + k0, alds1);
    async_cp16(bsrc + k0, blds0);
    async_cp16(bsrc + 16 * 768 + k0, blds1);
    __syncthreads();
    bfv8 af[4], bfr[4];
#pragma unroll
    for (int mi = 0; mi < 4; ++mi)
      af[mi] = *(const bfv8*)&As[(row0 + mi * 16 + li) * 32 + g8];
#pragma unroll
    for (int ni = 0; ni < 4; ++ni)
      bfr[ni] = *(const bfv8*)&Bs[(col0 + ni * 16 + li) * 32 + g8];
#pragma unroll
    for (int mi = 0; mi < 4; ++mi)
#pragma unroll
      for (int ni = 0; ni < 4; ++ni)
        acc[mi][ni] = MFMA(af[mi], bfr[ni], acc[mi][ni]);
    __syncthreads();
  }

  const int g4 = (lane >> 4) * 4;
#pragma unroll
  for (int mi = 0; mi < 4; ++mi) {
    int rbase = bm * 128 + row0 + mi * 16 + g4;
#pragma unroll
    for (int ni = 0; ni < 4; ++ni) {
      int col = bn * 128 + col0 + ni * 16 + li;
      int which = col / 768;
      int cm = col - which * 768;
      int head = cm >> 6, d = cm & 63;
      short* dst = (which == 0) ? Q : ((which == 1) ? K : V);
      float bias = qkvb[col];
      f32x4 a = acc[mi][ni];
#pragma unroll
      for (int j = 0; j < 4; ++j) {
        int t = rbase + j;
        int wdx = t / 196, n = t - wdx * 196;
        dst[((wdx * 12 + head) * 196 + n) * 64 + d] = f2bf(a[j] + bias);
      }
    }
  }
}

// ------------------------------------------------------------- attention
// one block per (window, head); 4 waves; K fragments straight from global,
// rel mini-GEMM B-fragments from global bf16 tables; LDS = Vt + P + rel
__global__ __launch_bounds__(256, 2) void attn_kernel(
    const short* __restrict__ Q, const short* __restrict__ K,
    const short* __restrict__ V, const short* __restrict__ Rhb,
    const short* __restrict__ Rwb, short* __restrict__ AO) {
  __shared__ short Vt[64 * 232];      // V^T [d][k], k padded 224(+8)
  __shared__ short Ps[4][16 * 232];   // per-wave P tile
  __shared__ short relh_w[4][16 * 32];
  __shared__ short relw_w[4][16 * 32];

  const int bh = blockIdx.x;
  const int wdx = bh / 12, head = bh - wdx * 12;
  const int tid = threadIdx.x, lane = tid & 63, wave = tid >> 6;
  const int li = lane & 15, g = lane >> 4, g8 = g * 8;
  const short* Qb = Q + bh * 12544;
  const short* Kb = K + bh * 12544;
  const short* Vb = V + bh * 12544;

  {
    int* z = (int*)Vt;
    for (int i = tid; i < 64 * 232 / 2; i += 256) z[i] = 0;
    int* z2 = (int*)Ps;
    for (int i = tid; i < 4 * 16 * 232 / 2; i += 256) z2[i] = 0;
  }
  __syncthreads();
  for (int t = tid; t < 784; t += 256) {  // V transpose: 98 key-pairs x 8 segs
    int dseg = t / 98, kp = t - dseg * 98, d0 = dseg * 8;
    s16x8 a = *(const s16x8*)(Vb + (2 * kp) * 64 + d0);
    s16x8 b = *(const s16x8*)(Vb + (2 * kp + 1) * 64 + d0);
#pragma unroll
    for (int i = 0; i < 8; ++i)
      *(short2*)&Vt[(d0 + i) * 232 + 2 * kp] = make_short2(a[i], b[i]);
  }
  __syncthreads();

  short* myP = Ps[wave];
  short* myRh = relh_w[wave];
  short* myRw = relw_w[wave];

  for (int mt = wave; mt < 13; mt += 4) {
    const int m0 = mt * 16;
    int qrow = m0 + li;
    if (qrow > 195) qrow = 195;
    const bfv8 qa0 = *(const bfv8*)(Qb + qrow * 64 + g8);
    const bfv8 qa1 = *(const bfv8*)(Qb + qrow * 64 + 32 + g8);

    // rel-pos mini-GEMMs: relall[m][p] = q[m] . rel_pos[p]
#pragma unroll
    for (int n = 0; n < 2; ++n) {
      const bfv8 rh0 = *(const bfv8*)(Rhb + (n * 16 + li) * 64 + g8);
      const bfv8 rh1 = *(const bfv8*)(Rhb + (n * 16 + li) * 64 + 32 + g8);
      f32x4 th = (f32x4){0.f, 0.f, 0.f, 0.f};
      th = MFMA(qa0, rh0, th);
      th = MFMA(qa1, rh1, th);
      const bfv8 rw0 = *(const bfv8*)(Rwb + (n * 16 + li) * 64 + g8);
      const bfv8 rw1 = *(const bfv8*)(Rwb + (n * 16 + li) * 64 + 32 + g8);
      f32x4 tw = (f32x4){0.f, 0.f, 0.f, 0.f};
      tw = MFMA(qa0, rw0, tw);
      tw = MFMA(qa1, rw1, tw);
#pragma unroll
      for (int j = 0; j < 4; ++j) {
        myRh[(g * 4 + j) * 32 + n * 16 + li] = f2bf(th[j]);
        myRw[(g * 4 + j) * 32 + n * 16 + li] = f2bf(tw[j]);
      }
    }

    // S = Q K^T (K fragments from global; L1/L2-hot, 25 KB per block)
    f32x4 sa[13];
#pragma unroll
    for (int nt = 0; nt < 13; ++nt) {
      int krow = nt * 16 + li;
      if (krow > 195) krow = 195;
      const bfv8 kb0 = *(const bfv8*)(Kb + krow * 64 + g8);
      const bfv8 kb1 = *(const bfv8*)(Kb + krow * 64 + 32 + g8);
      f32x4 t0 = (f32x4){0.f, 0.f, 0.f, 0.f};
      t0 = MFMA(qa0, kb0, t0);
      sa[nt] = MFMA(qa1, kb1, t0);
    }

    int hrj[4], wrj[4];
#pragma unroll
    for (int j = 0; j < 4; ++j) {
      int r = m0 + g * 4 + j;
      hrj[j] = r / 14;
      wrj[j] = r - hrj[j] * 14;
    }
    float mx[4] = {-3e38f, -3e38f, -3e38f, -3e38f};
#pragma unroll
    for (int nt = 0; nt < 13; ++nt) {
      int c = nt * 16 + li;
      bool valid = c < 196;
      int kh = c / 14;
      int kw = c - kh * 14;
#pragma unroll
      for (int j = 0; j < 4; ++j) {
        float s;
        if (valid) {
          s = sa[nt][j] * 0.125f +
              bf2f(myRh[(g * 4 + j) * 32 + hrj[j] - kh + 13]) +
              bf2f(myRw[(g * 4 + j) * 32 + wrj[j] - kw + 13]);
        } else {
          s = -3e38f;
        }
        sa[nt][j] = s;
        mx[j] = fmaxf(mx[j], s);
      }
    }
#pragma unroll
    for (int j = 0; j < 4; ++j) {
      mx[j] = fmaxf(mx[j], __shfl_xor(mx[j], 1));
      mx[j] = fmaxf(mx[j], __shfl_xor(mx[j], 2));
      mx[j] = fmaxf(mx[j], __shfl_xor(mx[j], 4));
      mx[j] = fmaxf(mx[j], __shfl_xor(mx[j], 8));
    }
    float sum[4] = {0.f, 0.f, 0.f, 0.f};
#pragma unroll
    for (int nt = 0; nt < 13; ++nt) {
#pragma unroll
      for (int j = 0; j < 4; ++j) {
        float p = __expf(sa[nt][j] - mx[j]);
        sa[nt][j] = p;
        sum[j] += p;
      }
    }
#pragma unroll
    for (int j = 0; j < 4; ++j) {
      sum[j] += __shfl_xor(sum[j], 1);
      sum[j] += __shfl_xor(sum[j], 2);
      sum[j] += __shfl_xor(sum[j], 4);
      sum[j] += __shfl_xor(sum[j], 8);
    }
    float inv[4];
#pragma unroll
    for (int j = 0; j < 4; ++j) inv[j] = 1.0f / sum[j];

#pragma unroll
    for (int nt = 0; nt < 13; ++nt) {
      int c = nt * 16 + li;
#pragma unroll
      for (int j = 0; j < 4; ++j)
        myP[(g * 4 + j) * 232 + c] = f2bf(sa[nt][j] * inv[j]);
    }

    // O = P V
    f32x4 oa[4];
#pragma unroll
    for (int dn = 0; dn < 4; ++dn) oa[dn] = (f32x4){0.f, 0.f, 0.f, 0.f};
#pragma unroll
    for (int kt = 0; kt < 7; ++kt) {
      const bfv8 pa = *(const bfv8*)&myP[li * 232 + kt * 32 + g8];
#pragma unroll
      for (int dn = 0; dn < 4; ++dn) {
        const bfv8 vb = *(const bfv8*)&Vt[(dn * 16 + li) * 232 + kt * 32 + g8];
        oa[dn] = MFMA(pa, vb, oa[dn]);
      }
    }
#pragma unroll
    for (int dn = 0; dn < 4; ++dn)
#pragma unroll
      for (int j = 0; j < 4; ++j) {
        int r = m0 + g * 4 + j;
        if (r < 196)
          AO[(wdx * 196 + r) * 768 + head * 64 + dn * 16 + li] = f2bf(oa[dn][j]);
      }
  }
}

// ------------------------------------------------------------- proj gemm
__global__ __launch_bounds__(256) void proj_gemm(
    const short* __restrict__ AO, const short* __restrict__ Wp,
    const float* __restrict__ projb, float* __restrict__ out) {
  __shared__ short As[128 * 32];
  __shared__ short Bs[128 * 32];
  int bid = blockIdx.x;
  int wg = (bid & 7) * 294 + (bid >> 3);  // 2352 = 8*294
  int bm = wg / 6, bn = wg - bm * 6;
  const int tid = threadIdx.x, lane = tid & 63, wave = tid >> 6;
  const int row0 = (wave >> 1) * 64, col0 = (wave & 1) * 64;
  const int li = lane & 15, g8 = (lane >> 4) * 8;

  const int c0 = wave * 2;
  const int rr = c0 * 16 + (lane >> 2);
  const int seg = (lane & 3) * 8;
  const short* asrc = AO + (bm * 128 + rr) * 768 + seg;
  const short* bsrc = Wp + (bn * 128 + rr) * 768 + seg;
  short* alds0 = As + c0 * 512;
  short* alds1 = As + c0 * 512 + 512;
  short* blds0 = Bs + c0 * 512;
  short* blds1 = Bs + c0 * 512 + 512;

  f32x4 acc[4][4];
#pragma unroll
  for (int i = 0; i < 4; ++i)
#pragma unroll
    for (int j = 0; j < 4; ++j) acc[i][j] = (f32x4){0.f, 0.f, 0.f, 0.f};

  for (int k0 = 0; k0 < 768; k0 += 32) {
    async_cp16(asrc + k0, alds0);
    async_cp16(asrc + 16 * 768 + k0, alds1);
    async_cp16(bsrc + k0, blds0);
    async_cp16(bsrc + 16 * 768 + k0, blds1);
    __syncthreads();
    bfv8 af[4], bfr[4];
#pragma unroll
    for (int mi = 0; mi < 4; ++mi)
      af[mi] = *(const bfv8*)&As[(row0 + mi * 16 + li) * 32 + g8];
#pragma unroll
    for (int ni = 0; ni < 4; ++ni)
      bfr[ni] = *(const bfv8*)&Bs[(col0 + ni * 16 + li) * 32 + g8];
#pragma unroll
    for (int mi = 0; mi < 4; ++mi)
#pragma unroll
      for (int ni = 0; ni < 4; ++ni)
        acc[mi][ni] = MFMA(af[mi], bfr[ni], acc[mi][ni]);
    __syncthreads();
  }

  const int g4 = (lane >> 4) * 4;
#pragma unroll
  for (int mi = 0; mi < 4; ++mi) {
    int rbase = bm * 128 + row0 + mi * 16 + g4;
#pragma unroll
    for (int ni = 0; ni < 4; ++ni) {
      int col = bn * 128 + col0 + ni * 16 + li;
      float bias = projb[col];
      f32x4 a = acc[mi][ni];
#pragma unroll
      for (int j = 0; j < 4; ++j) {
        int t = rbase + j;
        int wdx = t / 196, n = t - wdx * 196;
        int b = wdx >> 4, wl = wdx & 15;
        int nh = n / 14;
        int hh = (wl >> 2) * 14 + nh;
        int ww = (wl & 3) * 14 + (n - nh * 14);
        out[((b * 56 + hh) * 56 + ww) * 768 + col] = a[j] + bias;
      }
    }
  }
}

// ------------------------------------------------------------- launch
extern "C" void kernel_launch(void* const* d_in, const int* in_sizes, int n_in,
                              void* d_out, int out_size, void* d_ws, size_t ws_size,
                              hipStream_t stream) {
  const float* x = (const float*)d_in[0];
  const float* qkv_w = (const float*)d_in[1];
  const float* qkv_b = (const float*)d_in[2];
  const float* proj_w = (const float*)d_in[3];
  const float* proj_b = (const float*)d_in[4];
  const float* rph = (const float*)d_in[5];
  const float* rpw = (const float*)d_in[6];
  float* out = (float*)d_out;

  char* ws = (char*)d_ws;
  short* Q  = (short*)(ws);
  short* K  = (short*)(ws + 77070336);
  short* V  = (short*)(ws + 154140672);
  short* AO = (short*)(ws + 231211008);
  short* Wq = (short*)(ws + 308281344);
  short* Wp = (short*)(ws + 311820288);
  // d_out doubles as scratch until proj_gemm overwrites it completely
  short* Xbf = (short*)d_out;
  short* Rhb = (short*)((char*)d_out + 77070336);
  short* Rwb = Rhb + 2048;

  hipLaunchKernelGGL(convert_all, dim3(39940), dim3(256), 0, stream,
                     x, qkv_w, proj_w, rph, rpw, Xbf, Wq, Wp, Rhb, Rwb);
  hipLaunchKernelGGL(qkv_gemm, dim3(7056), dim3(256), 0, stream,
                     Xbf, Wq, qkv_b, Q, K, V);
  hipLaunchKernelGGL(attn_kernel, dim3(3072), dim3(256), 0, stream,
                     Q, K, V, Rhb, Rwb, AO);
  hipLaunchKernelGGL(proj_gemm, dim3(2352), dim3(256), 0, stream,
                     AO, Wp, proj_b, out);
}

// Round 3
// 531.140 us; speedup vs baseline: 1.6929x; 1.4206x over previous
//
#include <hip/hip_runtime.h>
#include <stdint.h>

typedef __bf16 bfv8 __attribute__((ext_vector_type(8)));
typedef short s16x8 __attribute__((ext_vector_type(8)));
typedef short s16x4 __attribute__((ext_vector_type(4)));
typedef float f32x4 __attribute__((ext_vector_type(4)));
typedef float f32x16 __attribute__((ext_vector_type(16)));

#define MFMA(a, b, c) __builtin_amdgcn_mfma_f32_16x16x32_bf16(a, b, c, 0, 0, 0)
#define MFMA32(a, b, c) __builtin_amdgcn_mfma_f32_32x32x16_bf16(a, b, c, 0, 0, 0)

__device__ __forceinline__ short f2bf(float f) {
  union { float f; unsigned u; } v; v.f = f;
  unsigned r = v.u + 0x7FFFu + ((v.u >> 16) & 1u);
  return (short)(r >> 16);
}
__device__ __forceinline__ float bf2f(short s) {
  union { unsigned u; float f; } v; v.u = ((unsigned)(unsigned short)s) << 16;
  return v.f;
}
__device__ __forceinline__ unsigned pack2(float a, float b) {
  return (unsigned)(unsigned short)f2bf(a) | ((unsigned)(unsigned short)f2bf(b) << 16);
}
__device__ __forceinline__ bfv8 mkfrag(unsigned a, unsigned b, unsigned c, unsigned d) {
  union { unsigned u[4]; bfv8 v; } t; t.u[0] = a; t.u[1] = b; t.u[2] = c; t.u[3] = d;
  return t.v;
}

// async global->LDS, 16B per lane; lds base must be wave-uniform
__device__ __forceinline__ void async_cp16(const short* g, short* l) {
  auto gp = reinterpret_cast<const uint32_t __attribute__((address_space(1)))*>(
      reinterpret_cast<uintptr_t>(g));
  auto lp = reinterpret_cast<uint32_t __attribute__((address_space(3)))*>(
      reinterpret_cast<uintptr_t>(l));
  __builtin_amdgcn_global_load_lds(gp, lp, 16, 0, 0);
}

// ------------------------------------------------------------- convert pass
__global__ __launch_bounds__(256) void convert_all(
    const float* __restrict__ x, const float* __restrict__ qkvw,
    const float* __restrict__ projw, const float* __restrict__ rph,
    const float* __restrict__ rpw, short* __restrict__ Xbf,
    short* __restrict__ Wq, short* __restrict__ Wp, short* __restrict__ Rhb,
    short* __restrict__ Rwb) {
  const int NX = 9633792;   // 50176*192
  const int NW1 = 442368;   // 2304*768/4
  const int NW2 = 147456;   // 768*768/4
  const int NR = 512;       // 32*16
  int idx = blockIdx.x * 256 + threadIdx.x;
  if (idx < NX) {
    int t = idx / 192, cq = idx - t * 192;
    int wdx = t / 196, n = t - wdx * 196;
    int b = wdx >> 4, wl = wdx & 15;
    int nh = n / 14;
    int hh = (wl >> 2) * 14 + nh;
    int ww = (wl & 3) * 14 + (n - nh * 14);
    float4 v = *(const float4*)(x + ((b * 56 + hh) * 56 + ww) * 768 + cq * 4);
    s16x4 s = {f2bf(v.x), f2bf(v.y), f2bf(v.z), f2bf(v.w)};
    *(s16x4*)(Xbf + idx * 4) = s;
  } else if (idx < NX + NW1) {
    int i = idx - NX;
    float4 v = ((const float4*)qkvw)[i];
    s16x4 s = {f2bf(v.x), f2bf(v.y), f2bf(v.z), f2bf(v.w)};
    *(s16x4*)(Wq + i * 4) = s;
  } else if (idx < NX + NW1 + NW2) {
    int i = idx - NX - NW1;
    float4 v = ((const float4*)projw)[i];
    s16x4 s = {f2bf(v.x), f2bf(v.y), f2bf(v.z), f2bf(v.w)};
    *(s16x4*)(Wp + i * 4) = s;
  } else if (idx < NX + NW1 + NW2 + 2 * NR) {
    int i = idx - NX - NW1 - NW2;
    int which = i >> 9;
    int j = i & 511;
    int p = j >> 4, q = j & 15;
    const float* src = which ? rpw : rph;
    short* dst = which ? Rwb : Rhb;
    s16x4 s = {0, 0, 0, 0};
    if (p < 27) {
      float4 v = *(const float4*)(src + p * 64 + q * 4);
      s = (s16x4){f2bf(v.x), f2bf(v.y), f2bf(v.z), f2bf(v.w)};
    }
    *(s16x4*)(dst + p * 64 + q * 4) = s;
  }
}

// ------------------------------------------------------------- qkv gemm
__global__ __launch_bounds__(256) void qkv_gemm(
    const short* __restrict__ Xbf, const short* __restrict__ Wq,
    const float* __restrict__ qkvb, short* __restrict__ Q,
    short* __restrict__ K, short* __restrict__ V) {
  __shared__ short As[128 * 32];
  __shared__ short Bs[128 * 32];
  int bid = blockIdx.x;
  int wg = (bid & 7) * 882 + (bid >> 3);
  int bm = wg / 18, bn = wg - bm * 18;
  const int tid = threadIdx.x, lane = tid & 63, wave = tid >> 6;
  const int row0 = (wave >> 1) * 64, col0 = (wave & 1) * 64;
  const int li = lane & 15, g8 = (lane >> 4) * 8;

  const int c0 = wave * 2;
  const int rr = c0 * 16 + (lane >> 2);
  const int seg = (lane & 3) * 8;
  const short* asrc = Xbf + (bm * 128 + rr) * 768 + seg;
  const short* bsrc = Wq + (bn * 128 + rr) * 768 + seg;
  short* alds0 = As + c0 * 512;
  short* alds1 = As + c0 * 512 + 512;
  short* blds0 = Bs + c0 * 512;
  short* blds1 = Bs + c0 * 512 + 512;

  f32x4 acc[4][4];
#pragma unroll
  for (int i = 0; i < 4; ++i)
#pragma unroll
    for (int j = 0; j < 4; ++j) acc[i][j] = (f32x4){0.f, 0.f, 0.f, 0.f};

  for (int k0 = 0; k0 < 768; k0 += 32) {
    async_cp16(asrc + k0, alds0);
    async_cp16(asrc + 16 * 768 + k0, alds1);
    async_cp16(bsrc + k0, blds0);
    async_cp16(bsrc + 16 * 768 + k0, blds1);
    __syncthreads();
    bfv8 af[4], bfr[4];
#pragma unroll
    for (int mi = 0; mi < 4; ++mi)
      af[mi] = *(const bfv8*)&As[(row0 + mi * 16 + li) * 32 + g8];
#pragma unroll
    for (int ni = 0; ni < 4; ++ni)
      bfr[ni] = *(const bfv8*)&Bs[(col0 + ni * 16 + li) * 32 + g8];
#pragma unroll
    for (int mi = 0; mi < 4; ++mi)
#pragma unroll
      for (int ni = 0; ni < 4; ++ni)
        acc[mi][ni] = MFMA(af[mi], bfr[ni], acc[mi][ni]);
    __syncthreads();
  }

  const int g4 = (lane >> 4) * 4;
#pragma unroll
  for (int mi = 0; mi < 4; ++mi) {
    int rbase = bm * 128 + row0 + mi * 16 + g4;
#pragma unroll
    for (int ni = 0; ni < 4; ++ni) {
      int col = bn * 128 + col0 + ni * 16 + li;
      int which = col / 768;
      int cm = col - which * 768;
      int head = cm >> 6, d = cm & 63;
      short* dst = (which == 0) ? Q : ((which == 1) ? K : V);
      float bias = qkvb[col];
      f32x4 a = acc[mi][ni];
#pragma unroll
      for (int j = 0; j < 4; ++j) {
        int t = rbase + j;
        int wdx = t / 196, n = t - wdx * 196;
        dst[((wdx * 12 + head) * 196 + n) * 64 + d] = f2bf(a[j] + bias);
      }
    }
  }
}

// ------------------------------------------------------------- attention
// one block per (window, head); 8 waves (512 thr); 32x32x16 MFMA, swapped
// QK^T, in-register P exchange (no P LDS), no-max softmax, K staged in LDS.
__global__ __launch_bounds__(512, 4) void attn_kernel(
    const short* __restrict__ Q, const short* __restrict__ K,
    const short* __restrict__ V, const short* __restrict__ Rhb,
    const short* __restrict__ Rwb, short* __restrict__ AO) {
  __shared__ short Ks[196 * 64];    // K rows, 16B-chunk XOR swizzle
  __shared__ short Vt[64 * 204];    // V^T [d][k], k 0..203 (196.. zeroed)
  __shared__ short relh[224 * 28];  // relall_h[q][p]
  __shared__ short relw[224 * 28];
  __shared__ short2 hw[224];        // (13-hk, 13-wk) per k

  const int bh = blockIdx.x;
  const int wdx = bh / 12, head = bh - wdx * 12;
  const int tid = threadIdx.x, lane = tid & 63, wave = tid >> 6;
  const int l31 = lane & 31, hb = lane >> 5;
  const short* Qb = Q + bh * 12544;
  const short* Kb = K + bh * 12544;
  const short* Vb = V + bh * 12544;

  const int m0 = wave * 32;
  const int qv = (m0 + l31 > 195) ? 195 : m0 + l31;

  // ---- per-wave: Q fragments + rel mini-GEMMs (waves 0..6) ----
  bfv8 qf[4];
  if (wave < 7) {
    f32x16 ra = {0.f, 0.f, 0.f, 0.f, 0.f, 0.f, 0.f, 0.f,
                 0.f, 0.f, 0.f, 0.f, 0.f, 0.f, 0.f, 0.f};
    f32x16 rw_ = ra;
#pragma unroll
    for (int s = 0; s < 4; ++s) {
      qf[s] = *(const bfv8*)(Qb + qv * 64 + s * 16 + hb * 8);
      ra = MFMA32(*(const bfv8*)(Rhb + l31 * 64 + s * 16 + hb * 8), qf[s], ra);
      rw_ = MFMA32(*(const bfv8*)(Rwb + l31 * 64 + s * 16 + hb * 8), qf[s], rw_);
    }
#pragma unroll
    for (int reg = 0; reg < 16; ++reg) {
      int p = (reg & 3) + 8 * (reg >> 2) + 4 * hb;
      if (!(hb && reg >= 12)) {  // p < 28
        relh[(m0 + l31) * 28 + p] = f2bf(ra[reg]);
        relw[(m0 + l31) * 28 + p] = f2bf(rw_[reg]);
      }
    }
  }

  // ---- staging (all 8 waves) ----
  // zero Vt tail (k 196..203) for all d
  if (tid < 64) {
    s16x8 z = {0, 0, 0, 0, 0, 0, 0, 0};
    *(s16x8*)&Vt[tid * 204 + 196] = z;
  }
  // K rows -> LDS with 16B-chunk XOR swizzle
  for (int c = tid; c < 1568; c += 512) {
    int r = c >> 3, cc = c & 7;
    s16x8 v = *(const s16x8*)(Kb + r * 64 + cc * 8);
    *(s16x8*)&Ks[r * 64 + (((cc ^ (r & 7))) << 3)] = v;
  }
  // V transpose
  for (int t = tid; t < 784; t += 512) {
    int dseg = t / 98, kp = t - dseg * 98, d0 = dseg * 8;
    s16x8 a = *(const s16x8*)(Vb + (2 * kp) * 64 + d0);
    s16x8 b = *(const s16x8*)(Vb + (2 * kp + 1) * 64 + d0);
#pragma unroll
    for (int i = 0; i < 8; ++i)
      *(short2*)&Vt[(d0 + i) * 204 + 2 * kp] = make_short2(a[i], b[i]);
  }
  // hk/wk table
  if (tid < 224) {
    int kc = (tid > 195) ? 195 : tid;
    int hk = kc / 14, wk = kc - hk * 14;
    hw[tid] = make_short2((short)(13 - hk), (short)(13 - wk));
  }
  __syncthreads();

  if (wave >= 7) return;

  const int hq = qv / 14;
  const int wq = qv - hq * 14;
  const short* relhq = &relh[qv * 28 + hq];
  const short* relwq = &relw[qv * 28 + wq];

  f32x16 oacc0 = {0.f, 0.f, 0.f, 0.f, 0.f, 0.f, 0.f, 0.f,
                  0.f, 0.f, 0.f, 0.f, 0.f, 0.f, 0.f, 0.f};
  f32x16 oacc1 = oacc0;
  float psum = 0.f;

#pragma unroll
  for (int nt = 0; nt < 7; ++nt) {
    // ---- S^T tile = K * Q^T ----
    int krow = nt * 32 + l31;
    int krc = (krow > 195) ? 195 : krow;
    const int rb = krc * 64, rx = krc & 7;
    f32x16 st = {0.f, 0.f, 0.f, 0.f, 0.f, 0.f, 0.f, 0.f,
                 0.f, 0.f, 0.f, 0.f, 0.f, 0.f, 0.f, 0.f};
#pragma unroll
    for (int s = 0; s < 4; ++s) {
      bfv8 kf = *(const bfv8*)&Ks[rb + (((2 * s + hb) ^ rx) << 3)];
      st = MFMA32(kf, qf[s], st);
    }
    // ---- bias + exp + sum (no-max softmax; scores provably small) ----
    float pv[16];
    float lsum = 0.f;
#pragma unroll
    for (int reg = 0; reg < 16; ++reg) {
      int koff = (reg & 3) + 8 * (reg >> 2) + 4 * hb;
      int k = nt * 32 + koff;
      short2 dxy = hw[k];
      float b = bf2f(relhq[dxy.x]) + bf2f(relwq[dxy.y]);
      float sv = fmaf(st[reg], 0.125f, b);
      float e = __expf(sv);
      if (nt == 6) {
        if (reg >= 4) e = 0.f;
        else if (hb) e = 0.f;
      }
      pv[reg] = e;
      lsum += e;
    }
    psum += lsum;
    // ---- pack P to bf16 + cross-half exchange -> A-frags ----
    unsigned pk[8], xk[8];
#pragma unroll
    for (int i = 0; i < 8; ++i) pk[i] = pack2(pv[2 * i], pv[2 * i + 1]);
#pragma unroll
    for (int i = 0; i < 8; ++i) xk[i] = (unsigned)__shfl_xor((int)pk[i], 32);

    // s = 0 (k = nt*32 + 0..15)
    {
      bfv8 pf = mkfrag(hb ? xk[2] : pk[0], hb ? xk[3] : pk[1],
                       hb ? pk[2] : xk[0], hb ? pk[3] : xk[1]);
      int kb = nt * 32 + hb * 8;
      if (nt == 6 && hb) kb = 0;  // P words are zero there
      oacc0 = MFMA32(pf, *(const bfv8*)&Vt[l31 * 204 + kb], oacc0);
      oacc1 = MFMA32(pf, *(const bfv8*)&Vt[(32 + l31) * 204 + kb], oacc1);
    }
    // s = 1 (k = nt*32 + 16..31)
    {
      bfv8 pf = mkfrag(hb ? xk[6] : pk[4], hb ? xk[7] : pk[5],
                       hb ? pk[6] : xk[4], hb ? pk[7] : xk[5]);
      int kb = nt * 32 + 16 + hb * 8;
      if (nt == 6) kb = 0;  // P words are zero there
      oacc0 = MFMA32(pf, *(const bfv8*)&Vt[l31 * 204 + kb], oacc0);
      oacc1 = MFMA32(pf, *(const bfv8*)&Vt[(32 + l31) * 204 + kb], oacc1);
    }
  }

  // ---- normalize + store ----
  float inv = 1.f / (psum + __shfl_xor(psum, 32));
  short* AOr = AO + (wdx * 196) * 768 + head * 64;
#pragma unroll
  for (int reg = 0; reg < 16; ++reg) {
    int qoff = (reg & 3) + 8 * (reg >> 2) + 4 * hb;
    float invr = __shfl(inv, qoff);
    int q = m0 + qoff;
    if (q < 196) {
      AOr[q * 768 + l31] = f2bf(oacc0[reg] * invr);
      AOr[q * 768 + 32 + l31] = f2bf(oacc1[reg] * invr);
    }
  }
}

// ------------------------------------------------------------- proj gemm
__global__ __launch_bounds__(256) void proj_gemm(
    const short* __restrict__ AO, const short* __restrict__ Wp,
    const float* __restrict__ projb, float* __restrict__ out) {
  __shared__ short As[128 * 32];
  __shared__ short Bs[128 * 32];
  int bid = blockIdx.x;
  int wg = (bid & 7) * 294 + (bid >> 3);
  int bm = wg / 6, bn = wg - bm * 6;
  const int tid = threadIdx.x, lane = tid & 63, wave = tid >> 6;
  const int row0 = (wave >> 1) * 64, col0 = (wave & 1) * 64;
  const int li = lane & 15, g8 = (lane >> 4) * 8;

  const int c0 = wave * 2;
  const int rr = c0 * 16 + (lane >> 2);
  const int seg = (lane & 3) * 8;
  const short* asrc = AO + (bm * 128 + rr) * 768 + seg;
  const short* bsrc = Wp + (bn * 128 + rr) * 768 + seg;
  short* alds0 = As + c0 * 512;
  short* alds1 = As + c0 * 512 + 512;
  short* blds0 = Bs + c0 * 512;
  short* blds1 = Bs + c0 * 512 + 512;

  f32x4 acc[4][4];
#pragma unroll
  for (int i = 0; i < 4; ++i)
#pragma unroll
    for (int j = 0; j < 4; ++j) acc[i][j] = (f32x4){0.f, 0.f, 0.f, 0.f};

  for (int k0 = 0; k0 < 768; k0 += 32) {
    async_cp16(asrc + k0, alds0);
    async_cp16(asrc + 16 * 768 + k0, alds1);
    async_cp16(bsrc + k0, blds0);
    async_cp16(bsrc + 16 * 768 + k0, blds1);
    __syncthreads();
    bfv8 af[4], bfr[4];
#pragma unroll
    for (int mi = 0; mi < 4; ++mi)
      af[mi] = *(const bfv8*)&As[(row0 + mi * 16 + li) * 32 + g8];
#pragma unroll
    for (int ni = 0; ni < 4; ++ni)
      bfr[ni] = *(const bfv8*)&Bs[(col0 + ni * 16 + li) * 32 + g8];
#pragma unroll
    for (int mi = 0; mi < 4; ++mi)
#pragma unroll
      for (int ni = 0; ni < 4; ++ni)
        acc[mi][ni] = MFMA(af[mi], bfr[ni], acc[mi][ni]);
    __syncthreads();
  }

  const int g4 = (lane >> 4) * 4;
#pragma unroll
  for (int mi = 0; mi < 4; ++mi) {
    int rbase = bm * 128 + row0 + mi * 16 + g4;
#pragma unroll
    for (int ni = 0; ni < 4; ++ni) {
      int col = bn * 128 + col0 + ni * 16 + li;
      float bias = projb[col];
      f32x4 a = acc[mi][ni];
#pragma unroll
      for (int j = 0; j < 4; ++j) {
        int t = rbase + j;
        int wdx = t / 196, n = t - wdx * 196;
        int b = wdx >> 4, wl = wdx & 15;
        int nh = n / 14;
        int hh = (wl >> 2) * 14 + nh;
        int ww = (wl & 3) * 14 + (n - nh * 14);
        out[((b * 56 + hh) * 56 + ww) * 768 + col] = a[j] + bias;
      }
    }
  }
}

// ------------------------------------------------------------- launch
extern "C" void kernel_launch(void* const* d_in, const int* in_sizes, int n_in,
                              void* d_out, int out_size, void* d_ws, size_t ws_size,
                              hipStream_t stream) {
  const float* x = (const float*)d_in[0];
  const float* qkv_w = (const float*)d_in[1];
  const float* qkv_b = (const float*)d_in[2];
  const float* proj_w = (const float*)d_in[3];
  const float* proj_b = (const float*)d_in[4];
  const float* rph = (const float*)d_in[5];
  const float* rpw = (const float*)d_in[6];
  float* out = (float*)d_out;

  char* ws = (char*)d_ws;
  short* Q  = (short*)(ws);
  short* K  = (short*)(ws + 77070336);
  short* V  = (short*)(ws + 154140672);
  short* AO = (short*)(ws + 231211008);
  short* Wq = (short*)(ws + 308281344);
  short* Wp = (short*)(ws + 311820288);
  // d_out doubles as scratch until proj_gemm overwrites it completely
  short* Xbf = (short*)d_out;
  short* Rhb = (short*)((char*)d_out + 77070336);
  short* Rwb = Rhb + 2048;

  hipLaunchKernelGGL(convert_all, dim3(39940), dim3(256), 0, stream,
                     x, qkv_w, proj_w, rph, rpw, Xbf, Wq, Wp, Rhb, Rwb);
  hipLaunchKernelGGL(qkv_gemm, dim3(7056), dim3(256), 0, stream,
                     Xbf, Wq, qkv_b, Q, K, V);
  hipLaunchKernelGGL(attn_kernel, dim3(3072), dim3(512), 0, stream,
                     Q, K, V, Rhb, Rwb, AO);
  hipLaunchKernelGGL(proj_gemm, dim3(2352), dim3(256), 0, stream,
                     AO, Wp, proj_b, out);
}

// Round 4
// 461.681 us; speedup vs baseline: 1.9476x; 1.1504x over previous
//
#include <hip/hip_runtime.h>
#include <stdint.h>

typedef __bf16 bfv8 __attribute__((ext_vector_type(8)));
typedef short s16x8 __attribute__((ext_vector_type(8)));
typedef short s16x4 __attribute__((ext_vector_type(4)));
typedef float f32x4 __attribute__((ext_vector_type(4)));
typedef float f32x16 __attribute__((ext_vector_type(16)));

#define MFMA(a, b, c) __builtin_amdgcn_mfma_f32_16x16x32_bf16(a, b, c, 0, 0, 0)
#define MFMA32(a, b, c) __builtin_amdgcn_mfma_f32_32x32x16_bf16(a, b, c, 0, 0, 0)

__device__ __forceinline__ short f2bf(float f) {
  union { float f; unsigned u; } v; v.f = f;
  unsigned r = v.u + 0x7FFFu + ((v.u >> 16) & 1u);
  return (short)(r >> 16);
}
__device__ __forceinline__ float bf2f(short s) {
  union { unsigned u; float f; } v; v.u = ((unsigned)(unsigned short)s) << 16;
  return v.f;
}
__device__ __forceinline__ unsigned pack2(float a, float b) {
  return (unsigned)(unsigned short)f2bf(a) | ((unsigned)(unsigned short)f2bf(b) << 16);
}
__device__ __forceinline__ bfv8 mkfrag(unsigned a, unsigned b, unsigned c, unsigned d) {
  union { unsigned u[4]; bfv8 v; } t; t.u[0] = a; t.u[1] = b; t.u[2] = c; t.u[3] = d;
  return t.v;
}

// async global->LDS, 16B per lane; lds base must be wave-uniform
__device__ __forceinline__ void async_cp16(const short* g, short* l) {
  auto gp = reinterpret_cast<const uint32_t __attribute__((address_space(1)))*>(
      reinterpret_cast<uintptr_t>(g));
  auto lp = reinterpret_cast<uint32_t __attribute__((address_space(3)))*>(
      reinterpret_cast<uintptr_t>(l));
  __builtin_amdgcn_global_load_lds(gp, lp, 16, 0, 0);
}

// ------------------------------------------------------------- convert pass
__global__ __launch_bounds__(256) void convert_all(
    const float* __restrict__ x, const float* __restrict__ qkvw,
    const float* __restrict__ projw, const float* __restrict__ rph,
    const float* __restrict__ rpw, short* __restrict__ Xbf,
    short* __restrict__ Wq, short* __restrict__ Wp, short* __restrict__ Rhb,
    short* __restrict__ Rwb) {
  const int NX = 9633792;   // 50176*192
  const int NW1 = 442368;   // 2304*768/4
  const int NW2 = 147456;   // 768*768/4
  const int NR = 512;       // 32*16
  int idx = blockIdx.x * 256 + threadIdx.x;
  if (idx < NX) {
    int t = idx / 192, cq = idx - t * 192;
    int wdx = t / 196, n = t - wdx * 196;
    int b = wdx >> 4, wl = wdx & 15;
    int nh = n / 14;
    int hh = (wl >> 2) * 14 + nh;
    int ww = (wl & 3) * 14 + (n - nh * 14);
    float4 v = *(const float4*)(x + ((b * 56 + hh) * 56 + ww) * 768 + cq * 4);
    s16x4 s = {f2bf(v.x), f2bf(v.y), f2bf(v.z), f2bf(v.w)};
    *(s16x4*)(Xbf + idx * 4) = s;
  } else if (idx < NX + NW1) {
    int i = idx - NX;
    float4 v = ((const float4*)qkvw)[i];
    s16x4 s = {f2bf(v.x), f2bf(v.y), f2bf(v.z), f2bf(v.w)};
    *(s16x4*)(Wq + i * 4) = s;
  } else if (idx < NX + NW1 + NW2) {
    int i = idx - NX - NW1;
    float4 v = ((const float4*)projw)[i];
    s16x4 s = {f2bf(v.x), f2bf(v.y), f2bf(v.z), f2bf(v.w)};
    *(s16x4*)(Wp + i * 4) = s;
  } else if (idx < NX + NW1 + NW2 + 2 * NR) {
    int i = idx - NX - NW1 - NW2;
    int which = i >> 9;
    int j = i & 511;
    int p = j >> 4, q = j & 15;
    const float* src = which ? rpw : rph;
    short* dst = which ? Rwb : Rhb;
    s16x4 s = {0, 0, 0, 0};
    if (p < 27) {
      float4 v = *(const float4*)(src + p * 64 + q * 4);
      s = (s16x4){f2bf(v.x), f2bf(v.y), f2bf(v.z), f2bf(v.w)};
    }
    *(s16x4*)(dst + p * 64 + q * 4) = s;
  }
}

// ============================================================= 256^2 GEMMs
// BM=BN=256, BK=64, 512 thr (8 waves 2x4), per-wave 128x64 out.
// LDS: 2 bufs x (A[256][64] + B[256][64]) bf16 = 128 KB.
// Staging: global_load_lds w/ linear LDS dest + source-slot swizzle
//   LDS(r, s) = G(r, s ^ (r&7));  read slot = (kh*4+g) ^ (li&7)  -> 2-way only.
// Pipeline: stage(t+1) issued before COMPUTE(t); vmcnt(0)+raw barrier per tile.

#define GEMM_PRE()                                                            \
  const int tid = threadIdx.x, lane = tid & 63, w = tid >> 6;                 \
  const int wr = w >> 2, wc = w & 3;                                          \
  const int li = lane & 15, g = lane >> 4;                                    \
  const int lr = lane >> 3, ls = lane & 7;                                    \
  const int ss = ls ^ lr;                                                     \
  f32x4 acc[8][4];                                                            \
  _Pragma("unroll") for (int i = 0; i < 8; ++i)                               \
  _Pragma("unroll") for (int j = 0; j < 4; ++j)                               \
      acc[i][j] = (f32x4){0.f, 0.f, 0.f, 0.f};

#define GEMM_STAGE(buf, t)                                                    \
  {                                                                           \
    _Pragma("unroll") for (int q = 0; q < 4; ++q) {                           \
      async_cp16(Asrc + q * 8 * 768 + (t) * 64, &As[buf][(w * 32 + q * 8) * 64]); \
      async_cp16(Bsrc + q * 8 * 768 + (t) * 64, &Bs[buf][(w * 32 + q * 8) * 64]); \
    }                                                                         \
  }

#define GEMM_WAITBAR()                                                        \
  asm volatile("s_waitcnt vmcnt(0)" ::: "memory");                            \
  __builtin_amdgcn_sched_barrier(0);                                          \
  __builtin_amdgcn_s_barrier();

#define GEMM_COMPUTE(buf)                                                     \
  {                                                                           \
    const short* Ab = As[buf];                                                \
    const short* Bb = Bs[buf];                                                \
    bfv8 bfr[4][2];                                                           \
    _Pragma("unroll") for (int nf = 0; nf < 4; ++nf)                          \
    _Pragma("unroll") for (int kh = 0; kh < 2; ++kh)                          \
        bfr[nf][kh] = *(const bfv8*)&Bb[(wc * 64 + nf * 16 + li) * 64 +       \
                                        (((kh * 4 + g) ^ (li & 7)) * 8)];     \
    _Pragma("unroll") for (int mh = 0; mh < 2; ++mh) {                        \
      bfv8 af[4][2];                                                          \
      _Pragma("unroll") for (int mf = 0; mf < 4; ++mf)                        \
      _Pragma("unroll") for (int kh = 0; kh < 2; ++kh)                        \
          af[mf][kh] = *(const bfv8*)&Ab[(wr * 128 + mh * 64 + mf * 16 + li) * 64 + \
                                         (((kh * 4 + g) ^ (li & 7)) * 8)];    \
      __builtin_amdgcn_s_setprio(1);                                          \
      _Pragma("unroll") for (int mf = 0; mf < 4; ++mf)                        \
      _Pragma("unroll") for (int nf = 0; nf < 4; ++nf) {                      \
        acc[mh * 4 + mf][nf] = MFMA(af[mf][0], bfr[nf][0], acc[mh * 4 + mf][nf]); \
        acc[mh * 4 + mf][nf] = MFMA(af[mf][1], bfr[nf][1], acc[mh * 4 + mf][nf]); \
      }                                                                       \
      __builtin_amdgcn_s_setprio(0);                                          \
    }                                                                         \
  }

#define GEMM_LOOP()                                                           \
  GEMM_STAGE(0, 0);                                                           \
  _Pragma("unroll 1") for (int tt = 0; tt < 6; ++tt) {                        \
    GEMM_WAITBAR();                                                           \
    GEMM_STAGE(1, 2 * tt + 1);                                                \
    GEMM_COMPUTE(0);                                                          \
    GEMM_WAITBAR();                                                           \
    if (tt < 5) GEMM_STAGE(0, 2 * tt + 2);                                    \
    GEMM_COMPUTE(1);                                                          \
  }

// ------------------------------------------------------------- qkv gemm
__global__ __launch_bounds__(512, 2) void qkv_gemm(
    const short* __restrict__ Xbf, const short* __restrict__ Wq,
    const float* __restrict__ qkvb, short* __restrict__ Q,
    short* __restrict__ K, short* __restrict__ V) {
  __shared__ short As[2][256 * 64];
  __shared__ short Bs[2][256 * 64];
  // grid 1764 = 196 m-tiles x 9 n-tiles; bijective XCD swizzle (q=220, r=4)
  int bid = blockIdx.x;
  int xcd = bid & 7, pos = bid >> 3;
  int wgid = (xcd < 4) ? xcd * 221 + pos : 884 + (xcd - 4) * 220 + pos;
  int bm = wgid / 9, bn = wgid - bm * 9;

  GEMM_PRE();
  const short* Asrc = Xbf + (bm * 256 + w * 32 + lr) * 768 + ss * 8;
  const short* Bsrc = Wq + (bn * 256 + w * 32 + lr) * 768 + ss * 8;

  GEMM_LOOP();

  // epilogue: scatter into Q/K/V [window*head][196][64]
  short* dst = (bn < 3) ? Q : ((bn < 6) ? K : V);
  const int head = (bn % 3) * 4 + wc;
  float bias[4];
#pragma unroll
  for (int nf = 0; nf < 4; ++nf) bias[nf] = qkvb[bn * 256 + wc * 64 + nf * 16 + li];
#pragma unroll
  for (int mi = 0; mi < 8; ++mi) {
    int rbase = bm * 256 + wr * 128 + (mi >> 2) * 64 + (mi & 3) * 16 + g * 4;
#pragma unroll
    for (int j = 0; j < 4; ++j) {
      int trow = rbase + j;
      int wdx = trow / 196, n = trow - wdx * 196;
      int base = ((wdx * 12 + head) * 196 + n) * 64;
#pragma unroll
      for (int nf = 0; nf < 4; ++nf)
        dst[base + nf * 16 + li] = f2bf(acc[mi][nf][j] + bias[nf]);
    }
  }
}

// ------------------------------------------------------------- proj gemm
__global__ __launch_bounds__(512, 2) void proj_gemm(
    const short* __restrict__ AO, const short* __restrict__ Wp,
    const float* __restrict__ projb, float* __restrict__ out) {
  __shared__ short As[2][256 * 64];
  __shared__ short Bs[2][256 * 64];
  // grid 588 = 196 x 3; bijective XCD swizzle (q=73, r=4)
  int bid = blockIdx.x;
  int xcd = bid & 7, pos = bid >> 3;
  int wgid = (xcd < 4) ? xcd * 74 + pos : 296 + (xcd - 4) * 73 + pos;
  int bm = wgid / 3, bn = wgid - bm * 3;

  GEMM_PRE();
  const short* Asrc = AO + (bm * 256 + w * 32 + lr) * 768 + ss * 8;
  const short* Bsrc = Wp + (bn * 256 + w * 32 + lr) * 768 + ss * 8;

  GEMM_LOOP();

  // epilogue: window-unpartition scatter, f32 out
  float bias[4];
#pragma unroll
  for (int nf = 0; nf < 4; ++nf) bias[nf] = projb[bn * 256 + wc * 64 + nf * 16 + li];
  const int col0 = bn * 256 + wc * 64 + li;
#pragma unroll
  for (int mi = 0; mi < 8; ++mi) {
    int rbase = bm * 256 + wr * 128 + (mi >> 2) * 64 + (mi & 3) * 16 + g * 4;
#pragma unroll
    for (int j = 0; j < 4; ++j) {
      int trow = rbase + j;
      int wdx = trow / 196, n = trow - wdx * 196;
      int b = wdx >> 4, wl = wdx & 15;
      int nh = n / 14;
      int hh = (wl >> 2) * 14 + nh;
      int ww = (wl & 3) * 14 + (n - nh * 14);
      float* orow = out + ((b * 56 + hh) * 56 + ww) * 768 + col0;
#pragma unroll
      for (int nf = 0; nf < 4; ++nf)
        orow[nf * 16] = acc[mi][nf][j] + bias[nf];
    }
  }
}

// ------------------------------------------------------------- attention
// one block per (window, head); 8 waves (512 thr); 32x32x16 MFMA, swapped
// QK^T, in-register P exchange (no P LDS), no-max softmax, K staged in LDS.
__global__ __launch_bounds__(512, 4) void attn_kernel(
    const short* __restrict__ Q, const short* __restrict__ K,
    const short* __restrict__ V, const short* __restrict__ Rhb,
    const short* __restrict__ Rwb, short* __restrict__ AO) {
  __shared__ short Ks[196 * 64];    // K rows, 16B-chunk XOR swizzle
  __shared__ short Vt[64 * 204];    // V^T [d][k], k 0..203 (196.. zeroed)
  __shared__ short relh[224 * 28];  // relall_h[q][p]
  __shared__ short relw[224 * 28];
  __shared__ short2 hw[224];        // (13-hk, 13-wk) per k

  const int bh = blockIdx.x;
  const int wdx = bh / 12, head = bh - wdx * 12;
  const int tid = threadIdx.x, lane = tid & 63, wave = tid >> 6;
  const int l31 = lane & 31, hb = lane >> 5;
  const short* Qb = Q + bh * 12544;
  const short* Kb = K + bh * 12544;
  const short* Vb = V + bh * 12544;

  const int m0 = wave * 32;
  const int qv = (m0 + l31 > 195) ? 195 : m0 + l31;

  // ---- per-wave: Q fragments + rel mini-GEMMs (waves 0..6) ----
  bfv8 qf[4];
  if (wave < 7) {
    f32x16 ra = {0.f, 0.f, 0.f, 0.f, 0.f, 0.f, 0.f, 0.f,
                 0.f, 0.f, 0.f, 0.f, 0.f, 0.f, 0.f, 0.f};
    f32x16 rw_ = ra;
#pragma unroll
    for (int s = 0; s < 4; ++s) {
      qf[s] = *(const bfv8*)(Qb + qv * 64 + s * 16 + hb * 8);
      ra = MFMA32(*(const bfv8*)(Rhb + l31 * 64 + s * 16 + hb * 8), qf[s], ra);
      rw_ = MFMA32(*(const bfv8*)(Rwb + l31 * 64 + s * 16 + hb * 8), qf[s], rw_);
    }
#pragma unroll
    for (int reg = 0; reg < 16; ++reg) {
      int p = (reg & 3) + 8 * (reg >> 2) + 4 * hb;
      if (!(hb && reg >= 12)) {  // p < 28
        relh[(m0 + l31) * 28 + p] = f2bf(ra[reg]);
        relw[(m0 + l31) * 28 + p] = f2bf(rw_[reg]);
      }
    }
  }

  // ---- staging (all 8 waves) ----
  if (tid < 64) {
    s16x8 z = {0, 0, 0, 0, 0, 0, 0, 0};
    *(s16x8*)&Vt[tid * 204 + 196] = z;
  }
  for (int c = tid; c < 1568; c += 512) {
    int r = c >> 3, cc = c & 7;
    s16x8 v = *(const s16x8*)(Kb + r * 64 + cc * 8);
    *(s16x8*)&Ks[r * 64 + (((cc ^ (r & 7))) << 3)] = v;
  }
  for (int t = tid; t < 784; t += 512) {
    int dseg = t / 98, kp = t - dseg * 98, d0 = dseg * 8;
    s16x8 a = *(const s16x8*)(Vb + (2 * kp) * 64 + d0);
    s16x8 b = *(const s16x8*)(Vb + (2 * kp + 1) * 64 + d0);
#pragma unroll
    for (int i = 0; i < 8; ++i)
      *(short2*)&Vt[(d0 + i) * 204 + 2 * kp] = make_short2(a[i], b[i]);
  }
  if (tid < 224) {
    int kc = (tid > 195) ? 195 : tid;
    int hk = kc / 14, wk = kc - hk * 14;
    hw[tid] = make_short2((short)(13 - hk), (short)(13 - wk));
  }
  __syncthreads();

  if (wave >= 7) return;

  const int hq = qv / 14;
  const int wq = qv - hq * 14;
  const short* relhq = &relh[qv * 28 + hq];
  const short* relwq = &relw[qv * 28 + wq];

  f32x16 oacc0 = {0.f, 0.f, 0.f, 0.f, 0.f, 0.f, 0.f, 0.f,
                  0.f, 0.f, 0.f, 0.f, 0.f, 0.f, 0.f, 0.f};
  f32x16 oacc1 = oacc0;
  float psum = 0.f;

#pragma unroll
  for (int nt = 0; nt < 7; ++nt) {
    int krow = nt * 32 + l31;
    int krc = (krow > 195) ? 195 : krow;
    const int rb = krc * 64, rx = krc & 7;
    f32x16 st = {0.f, 0.f, 0.f, 0.f, 0.f, 0.f, 0.f, 0.f,
                 0.f, 0.f, 0.f, 0.f, 0.f, 0.f, 0.f, 0.f};
#pragma unroll
    for (int s = 0; s < 4; ++s) {
      bfv8 kf = *(const bfv8*)&Ks[rb + (((2 * s + hb) ^ rx) << 3)];
      st = MFMA32(kf, qf[s], st);
    }
    float pv[16];
    float lsum = 0.f;
#pragma unroll
    for (int reg = 0; reg < 16; ++reg) {
      int koff = (reg & 3) + 8 * (reg >> 2) + 4 * hb;
      int k = nt * 32 + koff;
      short2 dxy = hw[k];
      float b = bf2f(relhq[dxy.x]) + bf2f(relwq[dxy.y]);
      float sv = fmaf(st[reg], 0.125f, b);
      float e = __expf(sv);
      if (nt == 6) {
        if (reg >= 4) e = 0.f;
        else if (hb) e = 0.f;
      }
      pv[reg] = e;
      lsum += e;
    }
    psum += lsum;
    unsigned pk[8], xk[8];
#pragma unroll
    for (int i = 0; i < 8; ++i) pk[i] = pack2(pv[2 * i], pv[2 * i + 1]);
#pragma unroll
    for (int i = 0; i < 8; ++i) xk[i] = (unsigned)__shfl_xor((int)pk[i], 32);

    {
      bfv8 pf = mkfrag(hb ? xk[2] : pk[0], hb ? xk[3] : pk[1],
                       hb ? pk[2] : xk[0], hb ? pk[3] : xk[1]);
      int kb = nt * 32 + hb * 8;
      if (nt == 6 && hb) kb = 0;
      oacc0 = MFMA32(pf, *(const bfv8*)&Vt[l31 * 204 + kb], oacc0);
      oacc1 = MFMA32(pf, *(const bfv8*)&Vt[(32 + l31) * 204 + kb], oacc1);
    }
    {
      bfv8 pf = mkfrag(hb ? xk[6] : pk[4], hb ? xk[7] : pk[5],
                       hb ? pk[6] : xk[4], hb ? pk[7] : xk[5]);
      int kb = nt * 32 + 16 + hb * 8;
      if (nt == 6) kb = 0;
      oacc0 = MFMA32(pf, *(const bfv8*)&Vt[l31 * 204 + kb], oacc0);
      oacc1 = MFMA32(pf, *(const bfv8*)&Vt[(32 + l31) * 204 + kb], oacc1);
    }
  }

  float inv = 1.f / (psum + __shfl_xor(psum, 32));
  short* AOr = AO + (wdx * 196) * 768 + head * 64;
#pragma unroll
  for (int reg = 0; reg < 16; ++reg) {
    int qoff = (reg & 3) + 8 * (reg >> 2) + 4 * hb;
    float invr = __shfl(inv, qoff);
    int q = m0 + qoff;
    if (q < 196) {
      AOr[q * 768 + l31] = f2bf(oacc0[reg] * invr);
      AOr[q * 768 + 32 + l31] = f2bf(oacc1[reg] * invr);
    }
  }
}

// ------------------------------------------------------------- launch
extern "C" void kernel_launch(void* const* d_in, const int* in_sizes, int n_in,
                              void* d_out, int out_size, void* d_ws, size_t ws_size,
                              hipStream_t stream) {
  const float* x = (const float*)d_in[0];
  const float* qkv_w = (const float*)d_in[1];
  const float* qkv_b = (const float*)d_in[2];
  const float* proj_w = (const float*)d_in[3];
  const float* proj_b = (const float*)d_in[4];
  const float* rph = (const float*)d_in[5];
  const float* rpw = (const float*)d_in[6];
  float* out = (float*)d_out;

  char* ws = (char*)d_ws;
  short* Q  = (short*)(ws);
  short* K  = (short*)(ws + 77070336);
  short* V  = (short*)(ws + 154140672);
  short* AO = (short*)(ws + 231211008);
  short* Wq = (short*)(ws + 308281344);
  short* Wp = (short*)(ws + 311820288);
  // d_out doubles as scratch until proj_gemm overwrites it completely
  short* Xbf = (short*)d_out;
  short* Rhb = (short*)((char*)d_out + 77070336);
  short* Rwb = Rhb + 2048;

  hipLaunchKernelGGL(convert_all, dim3(39940), dim3(256), 0, stream,
                     x, qkv_w, proj_w, rph, rpw, Xbf, Wq, Wp, Rhb, Rwb);
  hipLaunchKernelGGL(qkv_gemm, dim3(1764), dim3(512), 0, stream,
                     Xbf, Wq, qkv_b, Q, K, V);
  hipLaunchKernelGGL(attn_kernel, dim3(3072), dim3(512), 0, stream,
                     Q, K, V, Rhb, Rwb, AO);
  hipLaunchKernelGGL(proj_gemm, dim3(588), dim3(512), 0, stream,
                     AO, Wp, proj_b, out);
}